// Round 5
// baseline (23067.993 us; speedup 1.0000x reference)
//
#include <hip/hip_runtime.h>

typedef unsigned short u16;
typedef u16 u16x8 __attribute__((ext_vector_type(8)));
typedef u16 u16x4 __attribute__((ext_vector_type(4)));
typedef short bf16x8 __attribute__((ext_vector_type(8)));
typedef float f32x4 __attribute__((ext_vector_type(4)));

#define B_   64
#define F_   128
#define H_   512
#define S_   512
#define T_   96
#define KIH  640
#define NBLK 256

// ---- workspace byte offsets ----
#define BAR_OFF   0ul            // unsigned arr[256] @0, gen @1024
#define HTC_OFF   4096ul         // f32 [512][64]   h transposed
#define XT_OFF    135168ul       // f32 [128][64]   x transposed
#define HPT2_OFF  167936ul       // f32 [64][512]   h@Wa1^T
#define GHT_OFF   299008ul       // f32 [1536][64]  h@Whh^T + bhh
#define CTP_OFF   692224ul       // f32 [4][512][64] context partials
#define DEN_OFF   1216512ul      // f32 [4][64]
#define WB_OFF    1310720ul      // u16 [512][512]  Wa2 bf16
#define ENCP_OFF  2097152ul      // u16 [64][512][512] enc@Wa2^T + ba (bf16)
#define ENCB_OFF  35651584ul     // u16 [64][512][512] enc bf16
// end: 69206016 (~66 MiB)

struct Params {
  const float *dec_input, *hidden, *Wa, *Wv, *Wih, *bih, *Whh, *bhh, *Wout, *bout;
  char* ws;
  float* out;
};

__device__ __forceinline__ float bf2f(u16 u) {
  return __uint_as_float(((unsigned)u) << 16);
}
__device__ __forceinline__ u16 f2bf(float f) {
  unsigned u = __float_as_uint(f);
  return (u16)((u + 0x7fffu + ((u >> 16) & 1u)) >> 16);
}
__device__ __forceinline__ float fast_tanh(float x) {
  float e2 = __expf(2.f * x);
  return 1.f - 2.f / (e2 + 1.f);
}
__device__ __forceinline__ float fast_sig(float x) { return 1.f / (1.f + __expf(-x)); }

// ---------------- precompute kernels (unchanged from r4) ----------------
__global__ __launch_bounds__(256) void transcode_enc(const float* __restrict__ enc,
                                                     u16* __restrict__ out) {
  int i = blockIdx.x * 256 + threadIdx.x;
  #pragma unroll
  for (int u = 0; u < 4; ++u) {
    int idx = i + u * 1048576;
    float4 v = ((const float4*)enc)[idx];
    u16x4 o;
    o[0] = f2bf(v.x); o[1] = f2bf(v.y); o[2] = f2bf(v.z); o[3] = f2bf(v.w);
    ((u16x4*)out)[idx] = o;
  }
}

__global__ __launch_bounds__(256) void transcode_wa(const float* __restrict__ Wa,
                                                    u16* __restrict__ WB) {
  int i = blockIdx.x * 256 + threadIdx.x;
  int n = i >> 7, k4 = (i & 127) << 2;
  float4 v = *(const float4*)(Wa + (size_t)n * 1024 + 512 + k4);
  u16x4 o;
  o[0] = f2bf(v.x); o[1] = f2bf(v.y); o[2] = f2bf(v.z); o[3] = f2bf(v.w);
  *(u16x4*)(WB + (size_t)n * 512 + k4) = o;
}

__global__ __launch_bounds__(256) void mfma_encproj(const u16* __restrict__ Abf,
                                                    const u16* __restrict__ Bbf,
                                                    const float* __restrict__ ba,
                                                    u16* __restrict__ C) {
  __shared__ u16 As[128 * 40];
  __shared__ u16 Bs[128 * 40];
  const int tid = threadIdx.x, lane = tid & 63, w = tid >> 6;
  const int m0 = blockIdx.x << 7, n0 = blockIdx.y << 7;
  const int r0 = lane & 15, kh = lane >> 4;
  f32x4 acc[2][8] = {};
  for (int k0 = 0; k0 < 512; k0 += 32) {
    #pragma unroll
    for (int i = 0; i < 2; ++i) {
      int e = tid + (i << 8);
      int row = e >> 2, g = e & 3;
      *(u16x8*)&As[row * 40 + (g << 3)] =
          *(const u16x8*)(Abf + (size_t)(m0 + row) * 512 + k0 + (g << 3));
      *(u16x8*)&Bs[row * 40 + (g << 3)] =
          *(const u16x8*)(Bbf + (size_t)(n0 + row) * 512 + k0 + (g << 3));
    }
    __syncthreads();
    bf16x8 a[2], bb[8];
    #pragma unroll
    for (int r = 0; r < 2; ++r)
      a[r] = *(const bf16x8*)&As[((w << 5) + (r << 4) + r0) * 40 + (kh << 3)];
    #pragma unroll
    for (int c = 0; c < 8; ++c)
      bb[c] = *(const bf16x8*)&Bs[((c << 4) + r0) * 40 + (kh << 3)];
    #pragma unroll
    for (int r = 0; r < 2; ++r)
      #pragma unroll
      for (int c = 0; c < 8; ++c)
        acc[r][c] = __builtin_amdgcn_mfma_f32_16x16x32_bf16(a[r], bb[c], acc[r][c], 0, 0, 0);
    __syncthreads();
  }
  #pragma unroll
  for (int c = 0; c < 8; ++c) {
    int n = n0 + (c << 4) + r0;
    float bav = ba[n];
    #pragma unroll
    for (int r = 0; r < 2; ++r) {
      int mbase = m0 + (w << 5) + (r << 4) + (kh << 2);
      #pragma unroll
      for (int t = 0; t < 4; ++t)
        C[(size_t)(mbase + t) * 512 + n] = f2bf(acc[r][c][t] + bav);
    }
  }
}

// ---------------- persistent decoder ----------------
union SMem {
  struct { float cL[16 * 520]; float dL[16]; } a;
  struct { float cs[8192]; float part[3072]; } bc;
};

__device__ __forceinline__ void gridbar(unsigned* arr, unsigned* gen,
                                        unsigned epoch) {
  __syncthreads();
  const int bid = blockIdx.x, tid = threadIdx.x;
  if (bid == 0) {
    if (tid > 0 && tid < NBLK) {
      while (__hip_atomic_load(&arr[tid], __ATOMIC_ACQUIRE,
                               __HIP_MEMORY_SCOPE_AGENT) < epoch)
        __builtin_amdgcn_s_sleep(1);
    }
    __syncthreads();
    if (tid == 0) {
      __threadfence();
      __hip_atomic_store(gen, epoch, __ATOMIC_RELEASE, __HIP_MEMORY_SCOPE_AGENT);
    }
  } else {
    if (tid == 0) {
      __threadfence();
      __hip_atomic_store(&arr[bid], epoch, __ATOMIC_RELEASE,
                         __HIP_MEMORY_SCOPE_AGENT);
      while (__hip_atomic_load(gen, __ATOMIC_ACQUIRE,
                               __HIP_MEMORY_SCOPE_AGENT) < epoch)
        __builtin_amdgcn_s_sleep(1);
    }
  }
  __syncthreads();
}

__global__ __launch_bounds__(1024, 4) void decoder_persistent(Params p) {
  float* HTC  = (float*)(p.ws + HTC_OFF);
  float* XT   = (float*)(p.ws + XT_OFF);
  float* HPT2 = (float*)(p.ws + HPT2_OFF);
  float* GHT  = (float*)(p.ws + GHT_OFF);
  float* CTP  = (float*)(p.ws + CTP_OFF);
  float* DEN  = (float*)(p.ws + DEN_OFF);
  const u16* ENCP = (const u16*)(p.ws + ENCP_OFF);
  const u16* ENCB = (const u16*)(p.ws + ENCB_OFF);
  unsigned* arr = (unsigned*)(p.ws + BAR_OFF);
  unsigned* gen = (unsigned*)(p.ws + BAR_OFF + 1024);

  const int tid = threadIdx.x, bid = blockIdx.x;
  const int lane = tid & 63;
  const int flat = (bid << 10) + tid;
  unsigned epoch = 0;

  __shared__ SMem sm;

  // ---- init: hidden -> HTC, dec_input -> XT ----
  if (flat < 32768) {
    HTC[(flat & 511) * 64 + (flat >> 9)] = p.hidden[flat];
  } else if (flat < 40960) {
    int i2 = flat - 32768;
    XT[(i2 & 127) * 64 + (i2 >> 7)] = p.dec_input[i2];
  }
  gridbar(arr, gen, ++epoch);

  // ---- phase C shared lambda: rows of {Wout, Wa1, Whh} dotted with h ----
  const int g = (bid << 2) + (tid >> 8);
  const int cb = tid & 63, kq = (tid >> 6) & 3, jj = tid >> 8;
  auto phaseC = [&](int t) {
    const int row0 = g, row1 = g + 1024, row2 = (g < 128) ? 2048 + g : -1;
    const float* w0 = (row0 < 128) ? p.Wout + (size_t)row0 * 512
                     : (row0 < 640) ? p.Wa + (size_t)(row0 - 128) * 1024
                                    : p.Whh + (size_t)(row0 - 640) * 512;
    const float* w1 = p.Whh + (size_t)(row1 - 640) * 512;
    const float* w2 = (row2 >= 0) ? p.Whh + (size_t)(row2 - 640) * 512 : w1;
    float a0 = 0.f, a1 = 0.f, a2 = 0.f;
    for (int kt = 0; kt < 4; ++kt) {
      float4* d4 = (float4*)sm.bc.cs;
      const float4* s4 = (const float4*)(HTC + kt * 8192);
      d4[tid] = s4[tid];
      d4[tid + 1024] = s4[tid + 1024];
      __syncthreads();
      const int kb = kq << 5;
      #pragma unroll 8
      for (int i = 0; i < 32; ++i) {
        int hl = kb + i;
        float hv = sm.bc.cs[(hl << 6) + cb];
        int k = (kt << 7) + hl;
        a0 += hv * w0[k];
        a1 += hv * w1[k];
        a2 += hv * w2[k];
      }
      __syncthreads();
    }
    sm.bc.part[((jj * 3 + 0) * 4 + kq) * 64 + cb] = a0;
    sm.bc.part[((jj * 3 + 1) * 4 + kq) * 64 + cb] = a1;
    sm.bc.part[((jj * 3 + 2) * 4 + kq) * 64 + cb] = a2;
    __syncthreads();
    if (kq == 0) {
      #pragma unroll
      for (int s = 0; s < 3; ++s) {
        int row = (s == 0) ? row0 : (s == 1) ? row1 : row2;
        if (row < 0) continue;
        float val = sm.bc.part[((jj * 3 + s) * 4 + 0) * 64 + cb] +
                    sm.bc.part[((jj * 3 + s) * 4 + 1) * 64 + cb] +
                    sm.bc.part[((jj * 3 + s) * 4 + 2) * 64 + cb] +
                    sm.bc.part[((jj * 3 + s) * 4 + 3) * 64 + cb];
        if (row < 128) {
          if (t >= 0) {
            val += p.bout[row];
            p.out[((size_t)cb * T_ + t) * F_ + row] = val;
            XT[(row << 6) + cb] = val;
          }
        } else if (row < 640) {
          HPT2[((size_t)cb << 9) + (row - 128)] = val;
        } else {
          GHT[((row - 640) << 6) + cb] = val + p.bhh[row - 640];
        }
      }
    }
    __syncthreads();
  };

  phaseC(-1);
  gridbar(arr, gen, ++epoch);

  // hoisted attention constants
  float wv[8];
  *(float4*)wv       = *(const float4*)(p.Wv + (lane << 3));
  *(float4*)(wv + 4) = *(const float4*)(p.Wv + (lane << 3) + 4);
  const int ab = bid >> 2, sq = bid & 3;
  const int aw = tid >> 6;
  const int s0 = (sq << 7) + (aw << 3);
  const u16* pb = ENCP + (((size_t)(ab << 9) + s0) << 9) + (lane << 3);
  const u16* eb = ENCB + (((size_t)(ab << 9) + s0) << 9) + (lane << 3);

  for (int t = 0; t < T_; ++t) {
    // ---- phase A: scores + exp + partial context ----
    {
      float hp[8];
      const float* hpb = HPT2 + (ab << 9) + (lane << 3);
      *(float4*)hp       = *(const float4*)hpb;
      *(float4*)(hp + 4) = *(const float4*)(hpb + 4);
      float c[8] = {};
      float den = 0.f;
      #pragma unroll
      for (int i = 0; i < 8; ++i) {
        u16x8 pv = *(const u16x8*)(pb + ((size_t)i << 9));
        u16x8 ev = *(const u16x8*)(eb + ((size_t)i << 9));
        float acc = 0.f;
        #pragma unroll
        for (int r = 0; r < 8; ++r) acc += wv[r] * fast_tanh(hp[r] + bf2f(pv[r]));
        #pragma unroll
        for (int off = 32; off; off >>= 1) acc += __shfl_xor(acc, off);
        float e = __expf(acc);  // |score| <= ~11: un-normalized exp is safe
        den += e;
        #pragma unroll
        for (int r = 0; r < 8; ++r) c[r] += e * bf2f(ev[r]);
      }
      *(float4*)&sm.a.cL[aw * 520 + (lane << 3)]     = *(float4*)c;
      *(float4*)&sm.a.cL[aw * 520 + (lane << 3) + 4] = *(float4*)(c + 4);
      if (lane == 0) sm.a.dL[aw] = den;
      __syncthreads();
      if (tid < 512) {
        float v = 0.f;
        #pragma unroll
        for (int w2 = 0; w2 < 16; ++w2) v += sm.a.cL[w2 * 520 + tid];
        CTP[(size_t)((sq << 9) + tid) * 64 + ab] = v;
      } else if (tid < 576) {
        float d = (tid - 512 < 16) ? sm.a.dL[tid - 512] : 0.f;
        #pragma unroll
        for (int off = 32; off; off >>= 1) d += __shfl_xor(d, off);
        if (tid == 512) DEN[(sq << 6) + ab] = d;
      }
      __syncthreads();
    }
    gridbar(arr, gen, ++epoch);

    // ---- phase B: GRU gates + state update (blocks 0..127) ----
    if (bid < 128) {
      const int j = (bid << 2) + jj;
      const float inv = 1.f / (DEN[cb] + DEN[64 + cb] + DEN[128 + cb] + DEN[192 + cb]);
      const float* wr = p.Wih + (size_t)j * KIH;
      const float* wz = wr + (size_t)512 * KIH;
      const float* wn = wr + (size_t)1024 * KIH;
      float gr = 0.f, gz = 0.f, gn = 0.f;
      {
        const int kb = kq << 5;
        #pragma unroll 8
        for (int i = 0; i < 32; ++i) {
          int k = kb + i;
          float x = XT[(k << 6) + cb];
          gr += x * wr[k]; gz += x * wz[k]; gn += x * wn[k];
        }
      }
      for (int tt = 0; tt < 4; ++tt) {
        float4* d4 = (float4*)sm.bc.cs;
        const float4* q0 = (const float4*)(CTP + tt * 8192);
        const float4* q1 = (const float4*)(CTP + 32768 + tt * 8192);
        const float4* q2 = (const float4*)(CTP + 65536 + tt * 8192);
        const float4* q3 = (const float4*)(CTP + 98304 + tt * 8192);
        #pragma unroll
        for (int q = 0; q < 2; ++q) {
          int i4 = tid + (q << 10);
          float4 v = q0[i4], v1 = q1[i4], v2 = q2[i4], v3 = q3[i4];
          v.x += v1.x + v2.x + v3.x; v.y += v1.y + v2.y + v3.y;
          v.z += v1.z + v2.z + v3.z; v.w += v1.w + v2.w + v3.w;
          d4[i4] = v;
        }
        __syncthreads();
        const int kb = kq << 5;
        #pragma unroll 8
        for (int i = 0; i < 32; ++i) {
          int hl = kb + i;
          float cc = sm.bc.cs[(hl << 6) + cb] * inv;
          int kw = 128 + (tt << 7) + hl;
          gr += cc * wr[kw]; gz += cc * wz[kw]; gn += cc * wn[kw];
        }
        __syncthreads();
      }
      sm.bc.part[((jj * 3 + 0) * 4 + kq) * 64 + cb] = gr;
      sm.bc.part[((jj * 3 + 1) * 4 + kq) * 64 + cb] = gz;
      sm.bc.part[((jj * 3 + 2) * 4 + kq) * 64 + cb] = gn;
      __syncthreads();
      if (kq == 0) {
        float sr = 0.f, sz = 0.f, sn = 0.f;
        #pragma unroll
        for (int q = 0; q < 4; ++q) {
          sr += sm.bc.part[((jj * 3 + 0) * 4 + q) * 64 + cb];
          sz += sm.bc.part[((jj * 3 + 1) * 4 + q) * 64 + cb];
          sn += sm.bc.part[((jj * 3 + 2) * 4 + q) * 64 + cb];
        }
        float r = fast_sig(sr + p.bih[j] + GHT[(j << 6) + cb]);
        float z = fast_sig(sz + p.bih[512 + j] + GHT[((512 + j) << 6) + cb]);
        float nn = fast_tanh(sn + p.bih[1024 + j] + r * GHT[((1024 + j) << 6) + cb]);
        float h = HTC[(j << 6) + cb];
        HTC[(j << 6) + cb] = (1.f - z) * nn + z * h;
      }
      __syncthreads();
    }
    gridbar(arr, gen, ++epoch);

    // ---- phase C: projections from h_new ----
    phaseC(t);
    gridbar(arr, gen, ++epoch);
  }
}

extern "C" void kernel_launch(void* const* d_in, const int* in_sizes, int n_in,
                              void* d_out, int out_size, void* d_ws, size_t ws_size,
                              hipStream_t stream) {
  Params p;
  p.dec_input = (const float*)d_in[0];
  p.hidden    = (const float*)d_in[1];
  const float* enc = (const float*)d_in[2];
  p.Wa   = (const float*)d_in[5];
  const float* ba = (const float*)d_in[6];
  p.Wv   = (const float*)d_in[7];
  // d_in[8] bv cancels in softmax
  p.Wih  = (const float*)d_in[9];
  p.bih  = (const float*)d_in[10];
  p.Whh  = (const float*)d_in[11];
  p.bhh  = (const float*)d_in[12];
  p.Wout = (const float*)d_in[13];
  p.bout = (const float*)d_in[14];
  p.ws   = (char*)d_ws;
  p.out  = (float*)d_out;

  u16* WB   = (u16*)(p.ws + WB_OFF);
  u16* ENCP = (u16*)(p.ws + ENCP_OFF);
  u16* ENCB = (u16*)(p.ws + ENCB_OFF);

  hipMemsetAsync(d_ws, 0, 4096, stream);  // barrier state
  hipLaunchKernelGGL(transcode_enc, dim3(4096), dim3(256), 0, stream, enc, ENCB);
  hipLaunchKernelGGL(transcode_wa, dim3(256), dim3(256), 0, stream, p.Wa, WB);
  hipLaunchKernelGGL(mfma_encproj, dim3(256, 4), dim3(256), 0, stream,
                     ENCB, WB, ba, ENCP);

  void* args[] = {&p};
  hipLaunchCooperativeKernel((void*)decoder_persistent, dim3(NBLK), dim3(1024),
                             args, 0, stream);
}

// Round 6
// 11155.375 us; speedup vs baseline: 2.0679x; 2.0679x over previous
//
#include <hip/hip_runtime.h>

typedef unsigned short u16;
typedef _Float16 f16;
typedef f16 h2 __attribute__((ext_vector_type(2)));
typedef f16 h4 __attribute__((ext_vector_type(4)));
typedef f16 h8 __attribute__((ext_vector_type(8)));
typedef u16 u16x8 __attribute__((ext_vector_type(8)));
typedef float f32x4 __attribute__((ext_vector_type(4)));

#define B_   64
#define F_   128
#define H_   512
#define S_   512
#define T_   96

// ---- workspace byte offsets ----
#define ENCF_OFF  0ul            // f16 [64][512][512] enc
#define ENCP_OFF  33554432ul     // f16 [64][512][512] 2*(enc@Wa2^T + ba)
#define WTS_OFF   67108864ul     // h2  [1048576] packed transposed weights
#define WA2F_OFF  71303168ul     // f16 [512][512] Wa2
// end: 71827456 (~68.5 MiB)

// h2 element offsets inside WTS
#define WP4_BASE 0        // [64][2048][4]  cols 0..511: Wa1 rows; 512..2047: Whh rows
#define WX4_BASE 524288   // [16][1536][4]  Wih x-part
#define WC4_BASE 622592   // [64][1536][4]  Wih c-part
#define WO4_BASE 1015808  // [64][128][4]   Wout

__device__ __forceinline__ float fdot2(h2 a, h2 b, float c) {
#if __has_builtin(__builtin_amdgcn_fdot2)
  return __builtin_amdgcn_fdot2(a, b, c, false);
#else
  return c + (float)a[0] * (float)b[0] + (float)a[1] * (float)b[1];
#endif
}

// ---------------- enc f32 -> f16 (one-time) ----------------
__global__ __launch_bounds__(256) void transcode_enc(const float* __restrict__ enc,
                                                     f16* __restrict__ out) {
  int i = blockIdx.x * 256 + threadIdx.x;
  #pragma unroll
  for (int u = 0; u < 4; ++u) {
    int idx = i + u * 1048576;
    float4 v = ((const float4*)enc)[idx];
    h4 o = {(f16)v.x, (f16)v.y, (f16)v.z, (f16)v.w};
    ((h4*)out)[idx] = o;
  }
}

// ---------------- pack transposed f16 weights (one-time) ----------------
__global__ __launch_bounds__(256) void pack_weights(
    const float* __restrict__ Wa, const float* __restrict__ Whh,
    const float* __restrict__ Wih, const float* __restrict__ Wout,
    h2* __restrict__ WTS, f16* __restrict__ WA2F) {
  int i = blockIdx.x * 256 + threadIdx.x;
  if (i < 1048576) {
    float x0, x1;
    if (i < 524288) {                    // WP4: (k4*2048+n)*4+q
      int q = i & 3, t1 = i >> 2;
      int n = t1 & 2047, k4 = t1 >> 11;
      int k = ((k4 << 2) + q) << 1;
      if (n < 512) { x0 = Wa[n * 1024 + k]; x1 = Wa[n * 1024 + k + 1]; }
      else { x0 = Whh[(n - 512) * 512 + k]; x1 = Whh[(n - 512) * 512 + k + 1]; }
    } else if (i < 622592) {             // WX4
      int j = i - 524288;
      int q = j & 3, idx = j >> 2;
      int n = idx % 1536, k4 = idx / 1536;
      int k = ((k4 << 2) + q) << 1;
      x0 = Wih[n * 640 + k]; x1 = Wih[n * 640 + k + 1];
    } else if (i < 1015808) {            // WC4
      int j = i - 622592;
      int q = j & 3, idx = j >> 2;
      int n = idx % 1536, k4 = idx / 1536;
      int k = 128 + (((k4 << 2) + q) << 1);
      x0 = Wih[n * 640 + k]; x1 = Wih[n * 640 + k + 1];
    } else {                             // WO4
      int j = i - 1015808;
      int q = j & 3, idx = j >> 2;
      int n = idx & 127, k4 = idx >> 7;
      int k = ((k4 << 2) + q) << 1;
      x0 = Wout[n * 512 + k]; x1 = Wout[n * 512 + k + 1];
    }
    h2 o; o[0] = (f16)x0; o[1] = (f16)x1;
    WTS[i] = o;
  } else {                               // WA2F [n][k] from Wa[:,512:]
    int j = i - 1048576;
    int n = j >> 9, k = j & 511;
    WA2F[j] = (f16)Wa[n * 1024 + 512 + k];
  }
}

// ------- MFMA: ENCP[m][n] = 2*(sum_k ENCF[m][k]*WA2F[n][k] + ba[n]), f16 out -------
__global__ __launch_bounds__(256) void mfma_encproj(const u16* __restrict__ Abf,
                                                    const u16* __restrict__ Bbf,
                                                    const float* __restrict__ ba,
                                                    f16* __restrict__ C) {
  __shared__ u16 As[128 * 40];
  __shared__ u16 Bs[128 * 40];
  const int tid = threadIdx.x, lane = tid & 63, w = tid >> 6;
  const int m0 = blockIdx.x << 7, n0 = blockIdx.y << 7;
  const int r0 = lane & 15, kh = lane >> 4;
  f32x4 acc[2][8] = {};
  for (int k0 = 0; k0 < 512; k0 += 32) {
    #pragma unroll
    for (int i = 0; i < 2; ++i) {
      int e = tid + (i << 8);
      int row = e >> 2, g = e & 3;
      *(u16x8*)&As[row * 40 + (g << 3)] =
          *(const u16x8*)(Abf + (size_t)(m0 + row) * 512 + k0 + (g << 3));
      *(u16x8*)&Bs[row * 40 + (g << 3)] =
          *(const u16x8*)(Bbf + (size_t)(n0 + row) * 512 + k0 + (g << 3));
    }
    __syncthreads();
    h8 a[2], bb[8];
    #pragma unroll
    for (int r = 0; r < 2; ++r)
      a[r] = *(const h8*)&As[((w << 5) + (r << 4) + r0) * 40 + (kh << 3)];
    #pragma unroll
    for (int c = 0; c < 8; ++c)
      bb[c] = *(const h8*)&Bs[((c << 4) + r0) * 40 + (kh << 3)];
    #pragma unroll
    for (int r = 0; r < 2; ++r)
      #pragma unroll
      for (int c = 0; c < 8; ++c)
        acc[r][c] = __builtin_amdgcn_mfma_f32_16x16x32_f16(a[r], bb[c], acc[r][c], 0, 0, 0);
    __syncthreads();
  }
  #pragma unroll
  for (int c = 0; c < 8; ++c) {
    int n = n0 + (c << 4) + r0;
    float bav = ba[n];
    #pragma unroll
    for (int r = 0; r < 2; ++r) {
      int mbase = m0 + (w << 5) + (r << 4) + (kh << 2);
      #pragma unroll
      for (int t = 0; t < 4; ++t)
        C[(size_t)(mbase + t) * 512 + n] = (f16)(2.f * (acc[r][c][t] + bav));
    }
  }
}

// ---------------- persistent per-batch decoder: one block = one batch ----------------
__global__ __launch_bounds__(1024, 1) void decoder_batch(
    const f16* __restrict__ ENCF, const f16* __restrict__ ENCP2,
    const h2* __restrict__ WTS, const float* __restrict__ hidden,
    const float* __restrict__ dec_input, const float* __restrict__ Wv,
    const float* __restrict__ bih, const float* __restrict__ bhh,
    const float* __restrict__ bout, float* __restrict__ out) {
  const int b = blockIdx.x;
  const int tid = threadIdx.x;
  const int lane = tid & 63, w = tid >> 6;

  const h2* WP4 = WTS + WP4_BASE;
  const h2* WX4 = WTS + WX4_BASE;
  const h2* WC4 = WTS + WC4_BASE;
  const h2* WO4 = WTS + WO4_BASE;

  __shared__ __align__(16) float smf[12960];
  float* hp = smf;           // 512  (stores 2*h@Wa1^T)
  float* gh = smf + 512;     // 1536 (h@Whh^T + bhh)
  float* gx = smf + 2048;    // 1536 (x@Wihx^T + bih)
  float* hF = smf + 3584;    // 512
  float* cF = smf + 4096;    // 512
  float* dL = smf + 4608;    // 16
  float* denp = smf + 4624;  // 1
  float* scr = smf + 4640;   // 8320 scratch (att reduce / gc / out partials)
  __shared__ __align__(16) h2 hh2[256];
  __shared__ __align__(16) h2 ch2[256];
  __shared__ __align__(16) h2 xh2[64];

  // ---- init ----
  if (tid < 512) {
    float v = hidden[(b << 9) + tid];
    hF[tid] = v;
    float v2 = __shfl_xor(v, 1);
    if (!(lane & 1)) { h2 t2; t2[0] = (f16)v; t2[1] = (f16)v2; hh2[tid >> 1] = t2; }
  } else if (tid < 640) {
    int n = tid - 512;
    float v = dec_input[(b << 7) + n];
    float v2 = __shfl_xor(v, 1);
    if (!(lane & 1)) { h2 t2; t2[0] = (f16)v; t2[1] = (f16)v2; xh2[n >> 1] = t2; }
  }

  float wv[8];
  {
    const float* wp_ = Wv + (lane << 3);
    *(float4*)wv = *(const float4*)wp_;
    *(float4*)(wv + 4) = *(const float4*)(wp_ + 4);
  }
  const f16* pbase = ENCP2 + ((size_t)b << 18) + ((size_t)(w << 5) << 9) + (lane << 3);
  const f16* ebase = ENCF + ((size_t)b << 18) + ((size_t)(w << 5) << 9) + (lane << 3);
  __syncthreads();

  for (int t = 0; t < T_; ++t) {
    // ---- P1: hp = 2*h@Wa1^T, gh = h@Whh^T + bhh, gx = x@Wihx^T + bih ----
    {
      float a0 = 0.f, a1 = 0.f;
      const int n0 = tid, n1 = tid + 1024;
      #pragma unroll 4
      for (int k4 = 0; k4 < 64; ++k4) {
        h8 hv = *(const h8*)(hh2 + (k4 << 2));
        h8 w0 = *(const h8*)(WP4 + (((k4 << 11) + n0) << 2));
        h8 w1 = *(const h8*)(WP4 + (((k4 << 11) + n1) << 2));
        const h2* hq = (const h2*)&hv;
        const h2* w0q = (const h2*)&w0;
        const h2* w1q = (const h2*)&w1;
        #pragma unroll
        for (int q = 0; q < 4; ++q) {
          a0 = fdot2(hq[q], w0q[q], a0);
          a1 = fdot2(hq[q], w1q[q], a1);
        }
      }
      float b0 = 0.f;
      #pragma unroll
      for (int k4 = 0; k4 < 16; ++k4) {
        h8 xv = *(const h8*)(xh2 + (k4 << 2));
        h8 w0 = *(const h8*)(WX4 + ((k4 * 1536 + n0) << 2));
        const h2* xq = (const h2*)&xv;
        const h2* w0q = (const h2*)&w0;
        #pragma unroll
        for (int q = 0; q < 4; ++q) b0 = fdot2(xq[q], w0q[q], b0);
      }
      if (n0 < 512) hp[n0] = 2.f * a0;
      else gh[n0 - 512] = a0 + bhh[n0 - 512];
      gh[n1 - 512] = a1 + bhh[n1 - 512];
      gx[n0] = b0 + bih[n0];
      if (tid < 512) {
        float b1 = 0.f;
        #pragma unroll
        for (int k4 = 0; k4 < 16; ++k4) {
          h8 xv = *(const h8*)(xh2 + (k4 << 2));
          h8 w1 = *(const h8*)(WX4 + ((k4 * 1536 + 1024 + tid) << 2));
          const h2* xq = (const h2*)&xv;
          const h2* w1q = (const h2*)&w1;
          #pragma unroll
          for (int q = 0; q < 4; ++q) b1 = fdot2(xq[q], w1q[q], b1);
        }
        gx[1024 + tid] = b1 + bih[1024 + tid];
      }
    }
    __syncthreads();

    // ---- P2: scores + exp + context (wave w owns s = 32w..32w+31) ----
    {
      float hpv[8];
      *(float4*)hpv = *(const float4*)(hp + (lane << 3));
      *(float4*)(hpv + 4) = *(const float4*)(hp + (lane << 3) + 4);
      float c8[8] = {};
      float dpart = 0.f;
      #pragma unroll 4
      for (int i = 0; i < 32; ++i) {
        h8 pv = *(const h8*)(pbase + ((size_t)i << 9));
        h8 ev = *(const h8*)(ebase + ((size_t)i << 9));
        float sc = 0.f;
        #pragma unroll
        for (int r = 0; r < 8; ++r) {
          float e2 = __expf(hpv[r] + (float)pv[r]);     // e^{2x}
          sc += wv[r] * (1.f - __fdividef(2.f, e2 + 1.f));
        }
        #pragma unroll
        for (int off = 32; off; off >>= 1) sc += __shfl_xor(sc, off);
        float e = __expf(sc);  // |sc| <= ~23: safe un-normalized
        dpart += e;
        #pragma unroll
        for (int r = 0; r < 8; ++r) c8[r] += e * (float)ev[r];
      }
      *(float4*)&scr[w * 520 + (lane << 3)] = *(float4*)c8;
      *(float4*)&scr[w * 520 + (lane << 3) + 4] = *(float4*)(c8 + 4);
      if (lane == 0) dL[w] = dpart;
      __syncthreads();
      if (tid < 512) {
        float v = 0.f;
        #pragma unroll
        for (int w2 = 0; w2 < 16; ++w2) v += scr[w2 * 520 + tid];
        cF[tid] = v;
      } else if (tid >= 960) {
        float d = (lane < 16) ? dL[lane] : 0.f;
        #pragma unroll
        for (int off = 32; off; off >>= 1) d += __shfl_xor(d, off);
        if (lane == 0) denp[0] = d;
      }
      __syncthreads();
      if (tid < 256) {
        float inv = __fdividef(1.f, denp[0]);
        h2 t2; t2[0] = (f16)(cF[2 * tid] * inv); t2[1] = (f16)(cF[2 * tid + 1] * inv);
        ch2[tid] = t2;
      }
      __syncthreads();
    }

    // ---- P3: gc = c@Wihc^T; gates; h update; out projection ----
    {
      float g0 = 0.f;
      #pragma unroll 4
      for (int k4 = 0; k4 < 64; ++k4) {
        h8 cv = *(const h8*)(ch2 + (k4 << 2));
        h8 w0 = *(const h8*)(WC4 + ((k4 * 1536 + tid) << 2));
        const h2* cq = (const h2*)&cv;
        const h2* w0q = (const h2*)&w0;
        #pragma unroll
        for (int q = 0; q < 4; ++q) g0 = fdot2(cq[q], w0q[q], g0);
      }
      scr[tid] = g0;
      if (tid < 512) {
        float g1 = 0.f;
        #pragma unroll 4
        for (int k4 = 0; k4 < 64; ++k4) {
          h8 cv = *(const h8*)(ch2 + (k4 << 2));
          h8 w1 = *(const h8*)(WC4 + ((k4 * 1536 + 1024 + tid) << 2));
          const h2* cq = (const h2*)&cv;
          const h2* w1q = (const h2*)&w1;
          #pragma unroll
          for (int q = 0; q < 4; ++q) g1 = fdot2(cq[q], w1q[q], g1);
        }
        scr[1024 + tid] = g1;
      }
    }
    __syncthreads();
    if (tid < 512) {
      int j = tid;
      float grv = gx[j] + scr[j] + gh[j];
      float gzv = gx[512 + j] + scr[512 + j] + gh[512 + j];
      float gnx = gx[1024 + j] + scr[1024 + j];
      float r = __fdividef(1.f, 1.f + __expf(-grv));
      float z = __fdividef(1.f, 1.f + __expf(-gzv));
      float e2 = __expf(2.f * (gnx + r * gh[1024 + j]));
      float nn = 1.f - __fdividef(2.f, e2 + 1.f);
      float hn = (1.f - z) * nn + z * hF[j];
      hF[j] = hn;
      float v2 = __shfl_xor(hn, 1);
      if (!(lane & 1)) { h2 th; th[0] = (f16)hn; th[1] = (f16)v2; hh2[tid >> 1] = th; }
    }
    __syncthreads();
    {
      const int n = tid & 127, kc = tid >> 7;
      float a = 0.f;
      #pragma unroll
      for (int k4i = 0; k4i < 8; ++k4i) {
        int k4 = (kc << 3) + k4i;
        h8 hv = *(const h8*)(hh2 + (k4 << 2));
        h8 w0 = *(const h8*)(WO4 + (((k4 << 7) + n) << 2));
        const h2* hq = (const h2*)&hv;
        const h2* w0q = (const h2*)&w0;
        #pragma unroll
        for (int q = 0; q < 4; ++q) a = fdot2(hq[q], w0q[q], a);
      }
      scr[(kc << 7) + n] = a;
    }
    __syncthreads();
    if (tid < 128) {
      float v = bout[tid];
      #pragma unroll
      for (int kc = 0; kc < 8; ++kc) v += scr[(kc << 7) + tid];
      out[((size_t)b * T_ + t) * F_ + tid] = v;
      float v2 = __shfl_xor(v, 1);
      if (!(lane & 1)) { h2 tx; tx[0] = (f16)v; tx[1] = (f16)v2; xh2[tid >> 1] = tx; }
    }
    __syncthreads();
  }
}

extern "C" void kernel_launch(void* const* d_in, const int* in_sizes, int n_in,
                              void* d_out, int out_size, void* d_ws, size_t ws_size,
                              hipStream_t stream) {
  const float* dec_input = (const float*)d_in[0];
  const float* hidden    = (const float*)d_in[1];
  const float* enc       = (const float*)d_in[2];
  // d_in[3] expected_outputs, d_in[4] dec_output_len (fixed 96) unused
  const float* Wa   = (const float*)d_in[5];
  const float* ba   = (const float*)d_in[6];
  const float* Wv   = (const float*)d_in[7];
  // d_in[8] bv cancels in softmax
  const float* Wih  = (const float*)d_in[9];
  const float* bih  = (const float*)d_in[10];
  const float* Whh  = (const float*)d_in[11];
  const float* bhh  = (const float*)d_in[12];
  const float* Wout = (const float*)d_in[13];
  const float* bout = (const float*)d_in[14];
  float* out = (float*)d_out;

  char* ws = (char*)d_ws;
  f16* ENCF  = (f16*)(ws + ENCF_OFF);
  f16* ENCP2 = (f16*)(ws + ENCP_OFF);
  h2*  WTS   = (h2*)(ws + WTS_OFF);
  f16* WA2F  = (f16*)(ws + WA2F_OFF);

  hipLaunchKernelGGL(transcode_enc, dim3(4096), dim3(256), 0, stream, enc, ENCF);
  hipLaunchKernelGGL(pack_weights, dim3(5120), dim3(256), 0, stream,
                     Wa, Whh, Wih, Wout, WTS, WA2F);
  hipLaunchKernelGGL(mfma_encproj, dim3(256, 4), dim3(256), 0, stream,
                     (const u16*)ENCF, (const u16*)WA2F, ba, ENCP2);
  hipLaunchKernelGGL(decoder_batch, dim3(B_), dim3(1024), 0, stream,
                     ENCF, ENCP2, WTS, hidden, dec_input, Wv, bih, bhh, bout, out);
}

// Round 8
// 4562.212 us; speedup vs baseline: 5.0563x; 2.4452x over previous
//
#include <hip/hip_runtime.h>

typedef unsigned short u16;
typedef unsigned int u32;
typedef _Float16 f16;
typedef f16 h2 __attribute__((ext_vector_type(2)));
typedef f16 h4 __attribute__((ext_vector_type(4)));
typedef f16 h8 __attribute__((ext_vector_type(8)));
typedef u16 u16x8 __attribute__((ext_vector_type(8)));
typedef float f32x4 __attribute__((ext_vector_type(4)));

#define B_ 64
#define F_ 128
#define H_ 512
#define S_ 512
#define T_ 96
#define NB 256
#define NT 1024

// ---- workspace byte offsets ----
#define FLAG_OFF  0ul          // u32[256] @64B stride (16384 B)
#define GEN_OFF   16384ul      // u32[8] @64B stride
#define HP_OFF    20480ul      // f32 [64][512]
#define XF_OFF    151552ul     // f32 [64][128]
#define DEN_OFF   184320ul     // f32 [64][4]
#define CQ_OFF    185344ul     // u32 [64][4][256]  (f16x2 packed c partials, x 2^-13)
#define HNEW_OFF  447488ul     // f32 [2][64][512]
#define WTS_OFF   709632ul     // f16 [2359296]
#define ENCP_OFF  5428224ul    // f16 [64][512][512]  2*(enc@Wa2^T + ba)
#define ENCF_OFF  38982656ul   // f16 [64][512][512]  enc
// end: 72537088 (~69.2 MiB)

// f16-element offsets inside WTS
#define WA1_E  0        // [512][512]  Wa[:, :512]
#define WA2_E  262144   // [512][512]  Wa[:, 512:]
#define WHH_E  524288   // [1536][512]
#define WC_E   1310720  // [1536][512]  Wih[:, 128:]
#define WX_E   2097152  // [1536][128]  Wih[:, :128]
#define WOUT_E 2293760  // [128][512]
#define WTS_N  2359296

__device__ __forceinline__ float fdot2(h2 a, h2 b, float c) {
#if __has_builtin(__builtin_amdgcn_fdot2)
  return __builtin_amdgcn_fdot2(a, b, c, false);
#else
  return c + (float)a[0] * (float)b[0] + (float)a[1] * (float)b[1];
#endif
}
__device__ __forceinline__ u32 packh2(float a, float b) {
  h2 p; p[0] = (f16)a; p[1] = (f16)b;
  return __builtin_bit_cast(u32, p);
}
__device__ __forceinline__ h2 unpackh2(u32 v) { return __builtin_bit_cast(h2, v); }
// Cross-block data: exchange-RMW writes (coherent at MALL), relaxed atomic reads
// (no cache-invalidate; visibility validated by r2's gen-spin behavior).
__device__ __forceinline__ void xstf(float* p, float v) {
  __hip_atomic_exchange(p, v, __ATOMIC_RELAXED, __HIP_MEMORY_SCOPE_AGENT);
}
__device__ __forceinline__ void xstu(u32* p, u32 v) {
  __hip_atomic_exchange(p, v, __ATOMIC_RELAXED, __HIP_MEMORY_SCOPE_AGENT);
}
__device__ __forceinline__ float aldf(const float* p) {
  return __hip_atomic_load(p, __ATOMIC_RELAXED, __HIP_MEMORY_SCOPE_AGENT);
}
__device__ __forceinline__ u32 aldu(const u32* p) {
  return __hip_atomic_load(p, __ATOMIC_RELAXED, __HIP_MEMORY_SCOPE_AGENT);
}

// Fence-free grid barrier: flag array + 8-way replicated gen. Store-then-spin in
// ONE thread (no divergent-spin hazard); bounded spin (visible failure, no hang).
__device__ __forceinline__ void gridbar(u32* flags, u32* gen, unsigned ep) {
  __builtin_amdgcn_s_waitcnt(0);   // drain our exchange-RMWs (acked at MALL)
  __syncthreads();
  const int bid = blockIdx.x, tid = threadIdx.x;
  if (bid == 0) {
    if (tid >= 64 && tid < 319) {  // 255 pollers for blocks 1..255
      u32* pf = flags + (tid - 63) * 16;
      int guard = 0;
      while (__hip_atomic_load(pf, __ATOMIC_RELAXED, __HIP_MEMORY_SCOPE_AGENT) < ep) {
        __builtin_amdgcn_s_sleep(1);
        if (++guard > (1 << 16)) break;
      }
    }
    __syncthreads();
    if (tid < 8)
      __hip_atomic_exchange(gen + tid * 16, ep, __ATOMIC_RELAXED, __HIP_MEMORY_SCOPE_AGENT);
  } else {
    if (tid == 0) {
      __hip_atomic_exchange(flags + bid * 16, ep, __ATOMIC_RELAXED, __HIP_MEMORY_SCOPE_AGENT);
      u32* pg = gen + (bid & 7) * 16;
      int guard = 0;
      while (__hip_atomic_load(pg, __ATOMIC_RELAXED, __HIP_MEMORY_SCOPE_AGENT) < ep) {
        __builtin_amdgcn_s_sleep(1);
        if (++guard > (1 << 16)) break;
      }
    }
  }
  __syncthreads();
  asm volatile("" ::: "memory");
}

// ---------------- enc f32 -> f16 linear (one-time) ----------------
__global__ __launch_bounds__(256) void transcode_enc(const float* __restrict__ enc,
                                                     f16* __restrict__ out) {
  int i = blockIdx.x * 256 + threadIdx.x;
  #pragma unroll
  for (int u = 0; u < 4; ++u) {
    int idx = i + u * 1048576;
    float4 v = ((const float4*)enc)[idx];
    h4 o = {(f16)v.x, (f16)v.y, (f16)v.z, (f16)v.w};
    ((h4*)out)[idx] = o;
  }
}

// ---------------- pack all weights to f16 (one-time) ----------------
__global__ __launch_bounds__(256) void pack_weights(
    const float* __restrict__ Wa, const float* __restrict__ Whh,
    const float* __restrict__ Wih, const float* __restrict__ Wout,
    f16* __restrict__ WTS) {
  int i = blockIdx.x * 256 + threadIdx.x;
  if (i >= WTS_N) return;
  float x;
  if (i < WA2_E) {                       // Wa1
    int n = i >> 9, k = i & 511;
    x = Wa[(size_t)n * 1024 + k];
  } else if (i < WHH_E) {                // Wa2
    int j = i - WA2_E; int n = j >> 9, k = j & 511;
    x = Wa[(size_t)n * 1024 + 512 + k];
  } else if (i < WC_E) {                 // Whh
    int j = i - WHH_E; int n = j >> 9, k = j & 511;
    x = Whh[(size_t)n * 512 + k];
  } else if (i < WX_E) {                 // Wih c-part
    int j = i - WC_E; int n = j >> 9, k = j & 511;
    x = Wih[(size_t)n * 640 + 128 + k];
  } else if (i < WOUT_E) {               // Wih x-part
    int j = i - WX_E; int n = j >> 7, k = j & 127;
    x = Wih[(size_t)n * 640 + k];
  } else {                               // Wout
    int j = i - WOUT_E; int n = j >> 9, k = j & 511;
    x = Wout[(size_t)n * 512 + k];
  }
  WTS[i] = (f16)x;
}

// ------- MFMA: ENCP[m][n] = 2*(sum_k ENCF[m][k]*WA2[n][k] + ba[n]), f16, linear -------
__global__ __launch_bounds__(256) void mfma_encproj(const u16* __restrict__ Abf,
                                                    const u16* __restrict__ Bbf,
                                                    const float* __restrict__ ba,
                                                    f16* __restrict__ C) {
  __shared__ u16 As[128 * 40];
  __shared__ u16 Bs[128 * 40];
  const int tid = threadIdx.x, lane = tid & 63, w = tid >> 6;
  const int m0 = blockIdx.x << 7, n0 = blockIdx.y << 7;
  const int r0 = lane & 15, kh = lane >> 4;
  f32x4 acc[2][8] = {};
  for (int k0 = 0; k0 < 512; k0 += 32) {
    #pragma unroll
    for (int i = 0; i < 2; ++i) {
      int e = tid + (i << 8);
      int row = e >> 2, g = e & 3;
      *(u16x8*)&As[row * 40 + (g << 3)] =
          *(const u16x8*)(Abf + (size_t)(m0 + row) * 512 + k0 + (g << 3));
      *(u16x8*)&Bs[row * 40 + (g << 3)] =
          *(const u16x8*)(Bbf + (size_t)(n0 + row) * 512 + k0 + (g << 3));
    }
    __syncthreads();
    h8 a[2], bb[8];
    #pragma unroll
    for (int r = 0; r < 2; ++r)
      a[r] = *(const h8*)&As[((w << 5) + (r << 4) + r0) * 40 + (kh << 3)];
    #pragma unroll
    for (int c = 0; c < 8; ++c)
      bb[c] = *(const h8*)&Bs[((c << 4) + r0) * 40 + (kh << 3)];
    #pragma unroll
    for (int r = 0; r < 2; ++r)
      #pragma unroll
      for (int c = 0; c < 8; ++c)
        acc[r][c] = __builtin_amdgcn_mfma_f32_16x16x32_f16(a[r], bb[c], acc[r][c], 0, 0, 0);
    __syncthreads();
  }
  #pragma unroll
  for (int c = 0; c < 8; ++c) {
    int n = n0 + (c << 4) + r0;
    float bav = ba[n];
    #pragma unroll
    for (int r = 0; r < 2; ++r) {
      int mbase = m0 + (w << 5) + (r << 4) + (kh << 2);
      #pragma unroll
      for (int t = 0; t < 4; ++t)
        C[(size_t)(mbase + t) * 512 + n] = (f16)(2.f * (acc[r][c][t] + bav));
    }
  }
}

struct Params {
  const float *hidden, *dec_input, *Wv, *bih, *bhh, *bout;
  const f16 *ENCP, *ENCF, *WA1, *WHH, *WC, *WX, *WOUT;
  float *HP, *XF, *DEN, *HNEW;
  u32 *CQ, *flags, *gen;
  float *out;
};

__global__ __launch_bounds__(NT, 1) void decoder_phases(Params p) {
  __shared__ __align__(16) float hpL[512];
  __shared__ float cL[580];
  __shared__ float dWL[16];
  __shared__ __align__(16) h2 ch2L[4][256];
  __shared__ __align__(16) h2 hh2L[4][256];
  __shared__ __align__(16) h2 xh2L[4][64];
  __shared__ float hfL[4][32];
  __shared__ float invL[4];
  __shared__ float g1L[384], g2L[384];

  const int bid = blockIdx.x, tid = threadIdx.x;
  const int lane = tid & 63, w = tid >> 6;
  unsigned ep = 0;

  // phase-role constants
  const int ab = bid >> 2, asq = bid & 3;          // A: (batch, s-quarter)
  const int bg = bid >> 4;                         // B/C: 4-batch group
  const int rs = bid & 15;                         // B: h-slice; C: row-slice
  const int hsb = rs * 32;

  float wv2[8]; float wvs = 0.f;
  {
    const float* wp = p.Wv + lane * 8;
    #pragma unroll
    for (int e = 0; e < 8; ++e) { float v = wp[e]; wv2[e] = -2.f * v; wvs += v; }
  }

  // ================= init =================
  #pragma unroll
  for (int rep = 0; rep < 2; ++rep) {
    int idx = rep * NT + tid;
    int b4 = idx >> 9, i = idx & 511;
    float v = p.hidden[(size_t)(bg * 4 + b4) * 512 + i];
    float vp = __shfl_xor(v, 1);
    if (!(i & 1)) hh2L[b4][i >> 1] = h2{(f16)v, (f16)vp};
  }
  if (rs == 0) {
    #pragma unroll
    for (int rep = 0; rep < 2; ++rep) {
      int idx = rep * NT + tid;
      int b4 = idx >> 9, i = idx & 511;
      xstf(p.HNEW + (size_t)(bg * 4 + b4) * 512 + i,
           p.hidden[(size_t)(bg * 4 + b4) * 512 + i]);
    }
  } else if (rs == 1) {
    if (tid < 512) {
      int b = bg * 4 + (tid >> 7), n = tid & 127;
      xstf(p.XF + b * 128 + n, p.dec_input[b * 128 + n]);
    }
  }
  __syncthreads();
  if (tid < 160) {
    int row = rs * 40 + (tid >> 2), b4 = tid & 3;
    if (row < 512) {
      const f16* wr = p.WA1 + (size_t)row * 512;
      float acc = 0.f;
      #pragma unroll 8
      for (int k4 = 0; k4 < 64; ++k4) {
        h8 hv = *(const h8*)&hh2L[b4][k4 * 4];
        h8 wv = *(const h8*)(wr + k4 * 8);
        const h2 *hq = (const h2*)&hv, *wq = (const h2*)&wv;
        #pragma unroll
        for (int e = 0; e < 4; ++e) acc = fdot2(hq[e], wq[e], acc);
      }
      xstf(p.HP + (size_t)(bg * 4 + b4) * 512 + row, 2.f * acc);
    }
  }
  gridbar(p.flags, p.gen, ++ep);

  for (int step = 0; step < T_; ++step) {
    const int cur = step & 1, nxt = cur ^ 1;
    float* HNc = p.HNEW + cur * (64 * 512);
    float* HNn = p.HNEW + nxt * (64 * 512);

    // ================= A: scores + exp + c-partials over s-quarter =================
    if (tid < 512) {
      hpL[tid] = aldf(p.HP + (size_t)ab * 512 + tid);
      cL[(tid >> 3) * 9 + (tid & 7)] = 0.f;
    }
    __syncthreads();
    {
      float hp8[8];
      *(float4*)hp8 = *(const float4*)&hpL[lane * 8];
      *(float4*)(hp8 + 4) = *(const float4*)&hpL[lane * 8 + 4];
      const size_t sbase = (size_t)ab * 512 + asq * 128 + w * 8;
      const f16* pb = p.ENCP + (sbase << 9) + lane * 8;
      const f16* eb = p.ENCF + (sbase << 9) + lane * 8;
      float c8[8] = {};
      float den = 0.f;
      #pragma unroll
      for (int i = 0; i < 8; ++i) {
        h8 pv = *(const h8*)(pb + ((size_t)i << 9));
        float acc = wvs;
        #pragma unroll
        for (int e = 0; e < 8; ++e) {
          float e2 = __expf(hp8[e] + (float)pv[e]);     // e^{2x}
          acc += wv2[e] * __builtin_amdgcn_rcpf(e2 + 1.f);  // += wv*(1-2/(1+e^2x)) - wvs part
        }
        #pragma unroll
        for (int off = 32; off; off >>= 1) acc += __shfl_xor(acc, off);
        float es = __expf(acc);                          // |score| <= ~11: safe
        den += es;
        h8 ev = *(const h8*)(eb + ((size_t)i << 9));
        #pragma unroll
        for (int e = 0; e < 8; ++e) c8[e] += es * (float)ev[e];
      }
      #pragma unroll
      for (int e = 0; e < 8; ++e) atomicAdd(&cL[lane * 9 + e], c8[e]);
      if (lane == 0) dWL[w] = den;
    }
    __syncthreads();
    if (tid < 256) {
      int h0 = tid * 2;
      float lo = cL[(h0 >> 3) * 9 + (h0 & 7)] * 1.220703125e-4f;   // x 2^-13
      float hi = cL[((h0 + 1) >> 3) * 9 + ((h0 + 1) & 7)] * 1.220703125e-4f;
      xstu(p.CQ + (size_t)((ab << 2) | asq) * 256 + tid, packh2(lo, hi));
    } else if (tid == 256) {
      float d = 0.f;
      #pragma unroll
      for (int i = 0; i < 16; ++i) d += dWL[i];
      xstf(p.DEN + (ab << 2) + asq, d);
    }
    gridbar(p.flags, p.gen, ++ep);

    // ================= B: gates + h update (4 batches x 32-h slice) =================
    if (tid < 4) {
      float s = 0.f;
      #pragma unroll
      for (int sq = 0; sq < 4; ++sq) s += aldf(p.DEN + ((bg * 4 + tid) << 2) + sq);
      invL[tid] = 8192.f * __builtin_amdgcn_rcpf(s);     // 2^13 / den
    }
    __syncthreads();
    {
      int b4 = tid >> 8, pp = tid & 255;
      float lo = 0.f, hi = 0.f;
      #pragma unroll
      for (int sq = 0; sq < 4; ++sq) {
        h2 v = unpackh2(aldu(p.CQ + (size_t)(((bg * 4 + b4) << 2) | sq) * 256 + pp));
        lo += (float)v[0]; hi += (float)v[1];
      }
      float inv = invL[b4];
      ch2L[b4][pp] = h2{(f16)(lo * inv), (f16)(hi * inv)};
    }
    #pragma unroll
    for (int rep = 0; rep < 2; ++rep) {
      int idx = rep * NT + tid;
      int b4 = idx >> 9, i = idx & 511;
      float v = aldf(HNc + (size_t)(bg * 4 + b4) * 512 + i);
      float vp = __shfl_xor(v, 1);
      if (!(i & 1)) hh2L[b4][i >> 1] = h2{(f16)v, (f16)vp};
      int d = i - hsb;
      if (d >= 0 && d < 32) hfL[b4][d] = v;
    }
    if (tid < 256) {
      int b4 = tid >> 6, n2 = (tid & 63) * 2;
      float x0 = aldf(p.XF + (bg * 4 + b4) * 128 + n2);
      float x1 = aldf(p.XF + (bg * 4 + b4) * 128 + n2 + 1);
      xh2L[b4][n2 >> 1] = h2{(f16)x0, (f16)x1};
    }
    __syncthreads();
    if (tid < 384) {
      int b4 = tid & 3, g = (tid >> 2) % 3, r = tid / 12;
      int j = g * 512 + hsb + r;
      const f16* wc = p.WC + (size_t)j * 512;
      const f16* wh = p.WHH + (size_t)j * 512;
      const f16* wx = p.WX + (size_t)j * 128;
      float gc = 0.f, gh = 0.f, gx = 0.f;
      #pragma unroll 4
      for (int k4 = 0; k4 < 64; ++k4) {
        h8 cv = *(const h8*)&ch2L[b4][k4 * 4];
        h8 hv = *(const h8*)&hh2L[b4][k4 * 4];
        h8 wcv = *(const h8*)(wc + k4 * 8);
        h8 whv = *(const h8*)(wh + k4 * 8);
        const h2 *cq = (const h2*)&cv, *hq = (const h2*)&hv;
        const h2 *wcq = (const h2*)&wcv, *whq = (const h2*)&whv;
        #pragma unroll
        for (int e = 0; e < 4; ++e) {
          gc = fdot2(cq[e], wcq[e], gc);
          gh = fdot2(hq[e], whq[e], gh);
        }
      }
      #pragma unroll
      for (int k4 = 0; k4 < 16; ++k4) {
        h8 xv = *(const h8*)&xh2L[b4][k4 * 4];
        h8 wxv = *(const h8*)(wx + k4 * 8);
        const h2 *xq = (const h2*)&xv, *wxq = (const h2*)&wxv;
        #pragma unroll
        for (int e = 0; e < 4; ++e) gx = fdot2(xq[e], wxq[e], gx);
      }
      g1L[tid] = gc + gx + p.bih[j];
      g2L[tid] = gh + p.bhh[j];
    }
    __syncthreads();
    if (tid < 128) {
      int b4 = tid & 3, r = tid >> 2;
      int i0 = r * 12 + b4;
      float rr = __builtin_amdgcn_rcpf(1.f + __expf(-(g1L[i0] + g2L[i0])));
      float zz = __builtin_amdgcn_rcpf(1.f + __expf(-(g1L[i0 + 4] + g2L[i0 + 4])));
      float narg = g1L[i0 + 8] + rr * g2L[i0 + 8];
      float nn = 1.f - 2.f * __builtin_amdgcn_rcpf(1.f + __expf(2.f * narg));
      float hn = (1.f - zz) * nn + zz * hfL[b4][r];
      xstf(HNn + (size_t)(bg * 4 + b4) * 512 + hsb + r, hn);
    }
    gridbar(p.flags, p.gen, ++ep);

    // ================= C: hp, out, x from h_new =================
    #pragma unroll
    for (int rep = 0; rep < 2; ++rep) {
      int idx = rep * NT + tid;
      int b4 = idx >> 9, i = idx & 511;
      float v = aldf(HNn + (size_t)(bg * 4 + b4) * 512 + i);
      float vp = __shfl_xor(v, 1);
      if (!(i & 1)) hh2L[b4][i >> 1] = h2{(f16)v, (f16)vp};
    }
    __syncthreads();
    if (tid < 160) {
      int row = rs * 40 + (tid >> 2), b4 = tid & 3;
      const f16* wr = (row < 512) ? p.WA1 + (size_t)row * 512
                                  : p.WOUT + (size_t)(row - 512) * 512;
      float acc = 0.f;
      #pragma unroll 8
      for (int k4 = 0; k4 < 64; ++k4) {
        h8 hv = *(const h8*)&hh2L[b4][k4 * 4];
        h8 wv = *(const h8*)(wr + k4 * 8);
        const h2 *hq = (const h2*)&hv, *wq = (const h2*)&wv;
        #pragma unroll
        for (int e = 0; e < 4; ++e) acc = fdot2(hq[e], wq[e], acc);
      }
      int b = bg * 4 + b4;
      if (row < 512) {
        xstf(p.HP + (size_t)b * 512 + row, 2.f * acc);
      } else {
        int n = row - 512;
        float val = acc + p.bout[n];
        p.out[((size_t)b * T_ + step) * F_ + n] = val;
        xstf(p.XF + b * 128 + n, val);
      }
    }
    gridbar(p.flags, p.gen, ++ep);
  }
}

extern "C" void kernel_launch(void* const* d_in, const int* in_sizes, int n_in,
                              void* d_out, int out_size, void* d_ws, size_t ws_size,
                              hipStream_t stream) {
  const float* dec_input = (const float*)d_in[0];
  const float* hidden    = (const float*)d_in[1];
  const float* enc       = (const float*)d_in[2];
  // d_in[3] expected_outputs, d_in[4] dec_output_len (fixed 96) unused
  const float* Wa   = (const float*)d_in[5];
  const float* ba   = (const float*)d_in[6];
  const float* Wv   = (const float*)d_in[7];
  // d_in[8] bv cancels in softmax
  const float* Wih  = (const float*)d_in[9];
  const float* bih  = (const float*)d_in[10];
  const float* Whh  = (const float*)d_in[11];
  const float* bhh  = (const float*)d_in[12];
  const float* Wout = (const float*)d_in[13];
  const float* bout = (const float*)d_in[14];

  char* ws = (char*)d_ws;
  f16* WTS  = (f16*)(ws + WTS_OFF);
  f16* ENCP = (f16*)(ws + ENCP_OFF);
  f16* ENCF = (f16*)(ws + ENCF_OFF);

  Params p;
  p.hidden = hidden; p.dec_input = dec_input; p.Wv = Wv;
  p.bih = bih; p.bhh = bhh; p.bout = bout;
  p.ENCP = ENCP; p.ENCF = ENCF;
  p.WA1 = WTS + WA1_E; p.WHH = WTS + WHH_E; p.WC = WTS + WC_E;
  p.WX = WTS + WX_E; p.WOUT = WTS + WOUT_E;
  p.HP = (float*)(ws + HP_OFF); p.XF = (float*)(ws + XF_OFF);
  p.DEN = (float*)(ws + DEN_OFF); p.HNEW = (float*)(ws + HNEW_OFF);
  p.CQ = (u32*)(ws + CQ_OFF);
  p.flags = (u32*)(ws + FLAG_OFF); p.gen = (u32*)(ws + GEN_OFF);
  p.out = (float*)d_out;

  hipMemsetAsync(ws, 0, 20480, stream);   // flags + gen
  hipLaunchKernelGGL(transcode_enc, dim3(4096), dim3(256), 0, stream, enc, ENCF);
  hipLaunchKernelGGL(pack_weights, dim3(9216), dim3(256), 0, stream,
                     Wa, Whh, Wih, Wout, WTS);
  hipLaunchKernelGGL(mfma_encproj, dim3(256, 4), dim3(256), 0, stream,
                     (const u16*)ENCF, (const u16*)(WTS + WA2_E), ba, ENCP);

  void* args[] = {&p};
  hipLaunchCooperativeKernel((void*)decoder_phases, dim3(NB), dim3(NT), args, 0,
                             stream);
}